// Round 2
// baseline (1033.278 us; speedup 1.0000x reference)
//
#include <hip/hip_runtime.h>
#include <cstdint>

#define NR 8192
#define DIMK 512
#define NE 8192

// ---------------- MFMA path parameters ----------------
#define KP 1536            // 3 * DIMK (bf16x3 split)
#define GBK 32             // K-step
#define KSTEPS (KP / GBK)  // 48
#define NSPLIT 16          // code splits for candidate capture
#define TILE_BYTES 8192    // 128 rows x 32 k x 2B per K-step image
#define DELTA 0.02f

typedef __bf16 bf16x8 __attribute__((ext_vector_type(8)));
typedef float f32x4 __attribute__((ext_vector_type(4)));

// f32 fallback tiling (baseline, kept for small-ws fallback)
#define BM 128
#define BN 128
#define BK 16
#define ESPLIT 16
#define ERANGE (NE / ESPLIT)
#define ETILES (ERANGE / BN)
#define PM 64
#define PN 64
#define PK 16

// ---------------- Kernel: ||E_e||^2 ----------------
__global__ __launch_bounds__(256) void enorm_kernel(const float* __restrict__ E,
                                                    float* __restrict__ enorm) {
    int wave = threadIdx.x >> 6;
    int lane = threadIdx.x & 63;
    int row = blockIdx.x * 4 + wave;
    const float* er = E + (size_t)row * DIMK;
    float s = 0.f;
#pragma unroll
    for (int k = 0; k < DIMK / 64; ++k) {
        float v = er[lane + k * 64];
        s = fmaf(v, v, s);
    }
#pragma unroll
    for (int off = 32; off > 0; off >>= 1) s += __shfl_down(s, off, 64);
    if (lane == 0) enorm[row] = s;
}

// ---------------- Kernel: pack f32 -> bf16x3 tiled+swizzled ----------------
// A = [Xhi | Xlo | Xhi], B = [Ehi | Ehi | Elo]  (K' = 1536)
// Packed layout: per (tile128, kstep32): 8192-byte LDS image,
//   image byte for (r in 0..127, kk in 0..31) = (r*64 + kk*2) ^ ((r&7)<<4)
__global__ __launch_bounds__(256) void pack_kernel(const float* __restrict__ S,
                                                   uint8_t* __restrict__ P,
                                                   int isA) {
    int idx = blockIdx.x * 256 + threadIdx.x;   // NR*192 total
    int row = idx / 192;
    int c = idx - row * 192;
    int kglob = c * 8;
    int blk = kglob >> 9;       // 0,1,2
    int ksrc = kglob & 511;
    const float* src = S + (size_t)row * DIMK + ksrc;
    float4 f0 = *(const float4*)src;
    float4 f1 = *(const float4*)(src + 4);
    float xs[8] = {f0.x, f0.y, f0.z, f0.w, f1.x, f1.y, f1.z, f1.w};
    unsigned short o[8];
#pragma unroll
    for (int j = 0; j < 8; ++j) {
        float x = xs[j];
        __bf16 h = (__bf16)x;
        float rem = x - (float)h;
        __bf16 l = (__bf16)rem;
        __bf16 v;
        if (isA) v = (blk == 1) ? l : h;   // [hi, lo, hi]
        else     v = (blk == 2) ? l : h;   // [hi, hi, lo]
        o[j] = __builtin_bit_cast(unsigned short, v);
    }
    uint4 u;
    u.x = (uint32_t)o[0] | ((uint32_t)o[1] << 16);
    u.y = (uint32_t)o[2] | ((uint32_t)o[3] << 16);
    u.z = (uint32_t)o[4] | ((uint32_t)o[5] << 16);
    u.w = (uint32_t)o[6] | ((uint32_t)o[7] << 16);
    int mb = row >> 7, r = row & 127, kt = kglob >> 5, kk = kglob & 31;
    size_t base = ((size_t)mb * KSTEPS + kt) * TILE_BYTES;
    int byte = (r * 64 + kk * 2) ^ ((r & 7) << 4);
    *(uint4*)(P + base + byte) = u;
}

// ---------------- global -> LDS staging (8 KB, 256 threads) ----------------
__device__ __forceinline__ void stage_8k(void* lds, const void* g, int tid) {
    const int wid = tid >> 6;
    const int lane = tid & 63;
    using gu32 = const __attribute__((address_space(1))) uint32_t;
    using lu32 = __attribute__((address_space(3))) uint32_t;
    const uint8_t* gp = (const uint8_t*)g + (size_t)(wid * 1024 + lane * 16);
    uint8_t* lp = (uint8_t*)lds + wid * 1024;
    __builtin_amdgcn_global_load_lds((gu32*)gp, (lu32*)lp, 16, 0, 0);
    __builtin_amdgcn_global_load_lds((gu32*)(gp + 4096), (lu32*)(lp + 4096), 16, 0, 0);
}

__device__ __forceinline__ void t2merge(float& v1, int& i1, float& v2, int& i2,
                                        float ov, int oi) {
    if (ov < v1 || (ov == v1 && oi < i1)) {
        v2 = v1; i2 = i1; v1 = ov; i1 = oi;
    } else if (ov < v2 || (ov == v2 && oi < i2)) {
        v2 = ov; i2 = oi;
    }
}

// ---------------- Kernel: bf16x3 MFMA dist + top-2 capture ----------------
__global__ __launch_bounds__(256) void dist_mfma_kernel(
    const uint8_t* __restrict__ Ap, const uint8_t* __restrict__ Bp,
    const float* __restrict__ enorm,
    float* __restrict__ candv, int* __restrict__ candi) {
    __shared__ __align__(16) uint8_t As[TILE_BYTES];
    __shared__ __align__(16) uint8_t Bs[TILE_BYTES];
    __shared__ float t2v[128][2][2];
    __shared__ int t2i[128][2][2];

    const int tid = threadIdx.x;
    const int lane = tid & 63;
    const int wid = tid >> 6;
    const int wr = wid >> 1, wc = wid & 1;
    const int mb = blockIdx.y;       // 64 row-blocks of 128
    const int split = blockIdx.x;    // 16 splits of 512 codes
    const int lr = lane & 15;        // fragment row
    const int kq = lane >> 4;        // k-quarter

    float rv1 = 3.4e38f, rv2 = 3.4e38f;
    int ri1 = 0, ri2 = 0;

    const uint8_t* gA = Ap + (size_t)mb * KSTEPS * TILE_BYTES;

    for (int et = 0; et < 4; ++et) {
        const int nb = split * 4 + et;
        const uint8_t* gB = Bp + (size_t)nb * KSTEPS * TILE_BYTES;
        f32x4 acc[4][4];
#pragma unroll
        for (int mi = 0; mi < 4; ++mi)
#pragma unroll
            for (int ni = 0; ni < 4; ++ni)
                acc[mi][ni] = (f32x4){0.f, 0.f, 0.f, 0.f};

        for (int kt = 0; kt < KSTEPS; ++kt) {
            stage_8k(As, gA + (size_t)kt * TILE_BYTES, tid);
            stage_8k(Bs, gB + (size_t)kt * TILE_BYTES, tid);
            __syncthreads();
            bf16x8 af[4], bfr[4];
#pragma unroll
            for (int mi = 0; mi < 4; ++mi) {
                int row = wr * 64 + mi * 16 + lr;
                int byte = (row * 64 + kq * 16) ^ ((row & 7) << 4);
                af[mi] = *(const bf16x8*)(As + byte);
            }
#pragma unroll
            for (int ni = 0; ni < 4; ++ni) {
                int row = wc * 64 + ni * 16 + lr;
                int byte = (row * 64 + kq * 16) ^ ((row & 7) << 4);
                bfr[ni] = *(const bf16x8*)(Bs + byte);
            }
#pragma unroll
            for (int mi = 0; mi < 4; ++mi)
#pragma unroll
                for (int ni = 0; ni < 4; ++ni)
                    acc[mi][ni] = __builtin_amdgcn_mfma_f32_16x16x32_bf16(
                        af[mi], bfr[ni], acc[mi][ni], 0, 0, 0);
            __syncthreads();
        }

        // epilogue: s = enorm - 2*acc ; per-row top-2 over this 128-col tile
        const int e0 = nb * 128 + wc * 64;
#pragma unroll
        for (int mi = 0; mi < 4; ++mi) {
#pragma unroll
            for (int reg = 0; reg < 4; ++reg) {
                int rloc = wr * 64 + mi * 16 + kq * 4 + reg;
                float v1 = 3.4e38f, v2 = 3.4e38f;
                int i1 = 0, i2 = 0;
#pragma unroll
                for (int ni = 0; ni < 4; ++ni) {
                    int e = e0 + ni * 16 + lr;
                    float s = fmaf(-2.f, acc[mi][ni][reg], enorm[e]);
                    t2merge(v1, i1, v2, i2, s, e);
                }
#pragma unroll
                for (int m = 1; m <= 8; m <<= 1) {
                    float ov1 = __shfl_xor(v1, m, 64);
                    int oi1 = __shfl_xor(i1, m, 64);
                    float ov2 = __shfl_xor(v2, m, 64);
                    int oi2 = __shfl_xor(i2, m, 64);
                    t2merge(v1, i1, v2, i2, ov1, oi1);
                    t2merge(v1, i1, v2, i2, ov2, oi2);
                }
                if (lr == 0) {
                    t2v[rloc][wc][0] = v1; t2v[rloc][wc][1] = v2;
                    t2i[rloc][wc][0] = i1; t2i[rloc][wc][1] = i2;
                }
            }
        }
        __syncthreads();
        if (tid < 128) {
#pragma unroll
            for (int h = 0; h < 2; ++h)
#pragma unroll
                for (int c = 0; c < 2; ++c)
                    t2merge(rv1, ri1, rv2, ri2, t2v[tid][h][c], t2i[tid][h][c]);
        }
        __syncthreads();
    }

    if (tid < 128) {
        int row = mb * 128 + tid;
        size_t o = (size_t)row * (NSPLIT * 2) + split * 2;
        candv[o] = rv1; candi[o] = ri1;
        candv[o + 1] = rv2; candi[o + 1] = ri2;
    }
}

// ---------------- Kernel: fp64 refine of candidates -> argmin ----------------
__global__ __launch_bounds__(256) void refine_kernel(
    const float* __restrict__ X, const float* __restrict__ E,
    const float* __restrict__ candv, const int* __restrict__ candi,
    int* __restrict__ ind) {
    const int wid = threadIdx.x >> 6;
    const int lane = threadIdx.x & 63;
    const int row = blockIdx.x * 4 + wid;

    float v = 3.4e38f;
    int ci = 0;
    if (lane < 32) {
        v = candv[(size_t)row * 32 + lane];
        ci = candi[(size_t)row * 32 + lane];
    }
    float vmin = v;
#pragma unroll
    for (int off = 32; off > 0; off >>= 1)
        vmin = fminf(vmin, __shfl_xor(vmin, off, 64));

    unsigned long long mask = __ballot(lane < 32 && v <= vmin + DELTA);
    double bestd = 1e300;
    int besti = 0x7fffffff;
    const float* xr = X + (size_t)row * DIMK;
    while (mask) {
        int src = __ffsll((long long)mask) - 1;
        mask &= mask - 1;
        int e = __shfl(ci, src, 64);
        const float* er = E + (size_t)e * DIMK;
        double s = 0.0;
#pragma unroll
        for (int j = 0; j < 8; ++j) {
            double ev = (double)er[lane * 8 + j];
            double xv = (double)xr[lane * 8 + j];
            s += ev * (ev - 2.0 * xv);
        }
#pragma unroll
        for (int off = 32; off > 0; off >>= 1)
            s += __shfl_xor(s, off, 64);
        if (s < bestd || (s == bestd && e < besti)) { bestd = s; besti = e; }
    }
    if (lane == 0) ind[row] = besti;
}

// ------- f32 fallback: fused dist matmul + per-split argmin -------
__global__ __launch_bounds__(256) void dist_argmin_kernel(
    const float* __restrict__ X, const float* __restrict__ E,
    const float* __restrict__ enorm,
    float* __restrict__ pval, int* __restrict__ pidx) {
    __shared__ float xs[BK][BM + 4];
    __shared__ float es[BK][BN + 4];
    __shared__ float rv[BM][17];
    __shared__ int ri[BM][17];

    const int tid = threadIdx.x;
    const int row0 = blockIdx.y * BM;
    const int e_base = blockIdx.x * ERANGE;
    const int tx = tid & 15;
    const int ty = tid >> 4;

    float minv[8];
    int mini[8];
#pragma unroll
    for (int i = 0; i < 8; ++i) { minv[i] = 3.4e38f; mini[i] = 0; }

    const int lm = tid >> 1;
    const int lk = (tid & 1) * 8;

    for (int et = 0; et < ETILES; ++et) {
        const int e0 = e_base + et * BN;
        float acc[8][8];
#pragma unroll
        for (int i = 0; i < 8; ++i)
#pragma unroll
            for (int j = 0; j < 8; ++j) acc[i][j] = 0.f;

        for (int kt = 0; kt < DIMK / BK; ++kt) {
            const int k0 = kt * BK;
            {
                const float* src = X + (size_t)(row0 + lm) * DIMK + k0 + lk;
                float4 v0 = *(const float4*)(src);
                float4 v1 = *(const float4*)(src + 4);
                xs[lk + 0][lm] = v0.x; xs[lk + 1][lm] = v0.y;
                xs[lk + 2][lm] = v0.z; xs[lk + 3][lm] = v0.w;
                xs[lk + 4][lm] = v1.x; xs[lk + 5][lm] = v1.y;
                xs[lk + 6][lm] = v1.z; xs[lk + 7][lm] = v1.w;
            }
            {
                const float* src = E + (size_t)(e0 + lm) * DIMK + k0 + lk;
                float4 v0 = *(const float4*)(src);
                float4 v1 = *(const float4*)(src + 4);
                es[lk + 0][lm] = v0.x; es[lk + 1][lm] = v0.y;
                es[lk + 2][lm] = v0.z; es[lk + 3][lm] = v0.w;
                es[lk + 4][lm] = v1.x; es[lk + 5][lm] = v1.y;
                es[lk + 6][lm] = v1.z; es[lk + 7][lm] = v1.w;
            }
            __syncthreads();
#pragma unroll
            for (int k = 0; k < BK; ++k) {
                float4 a0 = *(const float4*)&xs[k][ty * 8];
                float4 a1 = *(const float4*)&xs[k][ty * 8 + 4];
                float4 b0 = *(const float4*)&es[k][tx * 8];
                float4 b1 = *(const float4*)&es[k][tx * 8 + 4];
                float av[8] = {a0.x, a0.y, a0.z, a0.w, a1.x, a1.y, a1.z, a1.w};
                float bv[8] = {b0.x, b0.y, b0.z, b0.w, b1.x, b1.y, b1.z, b1.w};
#pragma unroll
                for (int i = 0; i < 8; ++i)
#pragma unroll
                    for (int j = 0; j < 8; ++j)
                        acc[i][j] = fmaf(av[i], bv[j], acc[i][j]);
            }
            __syncthreads();
        }
#pragma unroll
        for (int j = 0; j < 8; ++j) {
            const int e = e0 + tx * 8 + j;
            const float en = enorm[e];
#pragma unroll
            for (int i = 0; i < 8; ++i) {
                const float s = fmaf(-2.f, acc[i][j], en);
                if (s < minv[i]) { minv[i] = s; mini[i] = e; }
            }
        }
    }
#pragma unroll
    for (int i = 0; i < 8; ++i) {
        rv[ty * 8 + i][tx] = minv[i];
        ri[ty * 8 + i][tx] = mini[i];
    }
    __syncthreads();
    if (tid < BM) {
        float bv = rv[tid][0];
        int bi = ri[tid][0];
#pragma unroll
        for (int t = 1; t < 16; ++t) {
            float vv = rv[tid][t];
            int ix = ri[tid][t];
            if (vv < bv || (vv == bv && ix < bi)) { bv = vv; bi = ix; }
        }
        const int row = row0 + tid;
        pval[(size_t)row * ESPLIT + blockIdx.x] = bv;
        pidx[(size_t)row * ESPLIT + blockIdx.x] = bi;
    }
}

__global__ __launch_bounds__(256) void reduce_argmin_kernel(
    const float* __restrict__ pval, const int* __restrict__ pidx,
    int* __restrict__ ind) {
    int r = blockIdx.x * blockDim.x + threadIdx.x;
    if (r >= NR) return;
    float bv = pval[(size_t)r * ESPLIT];
    int bi = pidx[(size_t)r * ESPLIT];
#pragma unroll
    for (int s = 1; s < ESPLIT; ++s) {
        float v = pval[(size_t)r * ESPLIT + s];
        int ix = pidx[(size_t)r * ESPLIT + s];
        if (v < bv || (v == bv && ix < bi)) { bv = v; bi = ix; }
    }
    ind[r] = bi;
}

// ------- proj: out = x + (x - E[ind]) @ W^T + b -------
__global__ __launch_bounds__(256) void proj_kernel(
    const float* __restrict__ X, const float* __restrict__ E,
    const int* __restrict__ ind,
    const float* __restrict__ W, const float* __restrict__ Bv,
    float* __restrict__ Out) {
    __shared__ float as_[PK][PM + 4];
    __shared__ float bs[PK][PN + 4];
    __shared__ int inds[PM];

    const int tid = threadIdx.x;
    const int row0 = blockIdx.y * PM;
    const int col0 = blockIdx.x * PN;

    if (tid < PM) inds[tid] = ind[row0 + tid];
    __syncthreads();

    const int tx = tid & 15;
    const int ty = tid >> 4;

    float acc[4][4];
#pragma unroll
    for (int i = 0; i < 4; ++i)
#pragma unroll
        for (int j = 0; j < 4; ++j) acc[i][j] = 0.f;

    const int lm = tid >> 2;
    const int lk = (tid & 3) * 4;

    for (int kt = 0; kt < DIMK / PK; ++kt) {
        const int k0 = kt * PK;
        {
            float4 xv = *(const float4*)(X + (size_t)(row0 + lm) * DIMK + k0 + lk);
            float4 qv = *(const float4*)(E + (size_t)inds[lm] * DIMK + k0 + lk);
            as_[lk + 0][lm] = xv.x - qv.x;
            as_[lk + 1][lm] = xv.y - qv.y;
            as_[lk + 2][lm] = xv.z - qv.z;
            as_[lk + 3][lm] = xv.w - qv.w;
        }
        {
            float4 wv = *(const float4*)(W + (size_t)(col0 + lm) * DIMK + k0 + lk);
            bs[lk + 0][lm] = wv.x; bs[lk + 1][lm] = wv.y;
            bs[lk + 2][lm] = wv.z; bs[lk + 3][lm] = wv.w;
        }
        __syncthreads();
#pragma unroll
        for (int k = 0; k < PK; ++k) {
            float4 a = *(const float4*)&as_[k][ty * 4];
            float4 b = *(const float4*)&bs[k][tx * 4];
            float av[4] = {a.x, a.y, a.z, a.w};
            float bvv[4] = {b.x, b.y, b.z, b.w};
#pragma unroll
            for (int i = 0; i < 4; ++i)
#pragma unroll
                for (int j = 0; j < 4; ++j)
                    acc[i][j] = fmaf(av[i], bvv[j], acc[i][j]);
        }
        __syncthreads();
    }

#pragma unroll
    for (int j = 0; j < 4; ++j) {
        const int col = col0 + tx * 4 + j;
        const float bias = Bv[col];
#pragma unroll
        for (int i = 0; i < 4; ++i) {
            const int row = row0 + ty * 4 + i;
            Out[(size_t)row * DIMK + col] =
                X[(size_t)row * DIMK + col] + acc[i][j] + bias;
        }
    }
}

extern "C" void kernel_launch(void* const* d_in, const int* in_sizes, int n_in,
                              void* d_out, int out_size, void* d_ws, size_t ws_size,
                              hipStream_t stream) {
    const float* X = (const float*)d_in[0];
    const float* E = (const float*)d_in[1];
    const float* W = (const float*)d_in[2];
    const float* B = (const float*)d_in[3];
    float* out = (float*)d_out;

    const size_t packBytes = (size_t)NR * KP * 2;     // 24 MB each
    const size_t needMFMA = packBytes * 2 + NE * 4 + (size_t)NR * 32 * 8 + NR * 4;

    if (ws_size >= needMFMA) {
        uint8_t* Ap = (uint8_t*)d_ws;
        uint8_t* Bp = Ap + packBytes;
        float* enorm = (float*)(Bp + packBytes);
        float* candv = enorm + NE;
        int* candi = (int*)(candv + (size_t)NR * 32);
        int* ind = candi + (size_t)NR * 32;

        hipLaunchKernelGGL(enorm_kernel, dim3(NE / 4), dim3(256), 0, stream, E, enorm);
        hipLaunchKernelGGL(pack_kernel, dim3(NR * 192 / 256), dim3(256), 0, stream,
                           X, Ap, 1);
        hipLaunchKernelGGL(pack_kernel, dim3(NE * 192 / 256), dim3(256), 0, stream,
                           E, Bp, 0);
        hipLaunchKernelGGL(dist_mfma_kernel, dim3(NSPLIT, NR / 128), dim3(256), 0,
                           stream, Ap, Bp, enorm, candv, candi);
        hipLaunchKernelGGL(refine_kernel, dim3(NR / 4), dim3(256), 0, stream,
                           X, E, candv, candi, ind);
        hipLaunchKernelGGL(proj_kernel, dim3(DIMK / PN, NR / PM), dim3(256), 0, stream,
                           X, E, ind, W, B, out);
    } else {
        float* enorm = (float*)d_ws;
        float* pval = enorm + NE;
        int* pidx = (int*)(pval + (size_t)NR * ESPLIT);
        int* ind = pidx + (size_t)NR * ESPLIT;

        hipLaunchKernelGGL(enorm_kernel, dim3(NE / 4), dim3(256), 0, stream, E, enorm);
        hipLaunchKernelGGL(dist_argmin_kernel, dim3(ESPLIT, NR / BM), dim3(256), 0,
                           stream, X, E, enorm, pval, pidx);
        hipLaunchKernelGGL(reduce_argmin_kernel, dim3(NR / 256), dim3(256), 0, stream,
                           pval, pidx, ind);
        hipLaunchKernelGGL(proj_kernel, dim3(DIMK / PN, NR / PM), dim3(256), 0, stream,
                           X, E, ind, W, B, out);
    }
}

// Round 3
// 839.862 us; speedup vs baseline: 1.2303x; 1.2303x over previous
//
#include <hip/hip_runtime.h>
#include <cstdint>

#define NR 8192
#define DIMK 512
#define NE 8192

// ---------------- MFMA path parameters ----------------
#define KP 1536            // 3 * DIMK (bf16x3 split)
#define GBK 32             // K-step
#define KSTEPS (KP / GBK)  // 48
#define TILE_BYTES 8192    // 128 rows x 32 k x 2B per K-step image
#define NBLK 64            // 64 col-blocks of 128 codes
#define DELTA 0.02f

typedef __bf16 bf16x8 __attribute__((ext_vector_type(8)));
typedef float f32x4 __attribute__((ext_vector_type(4)));

// f32 fallback tiling
#define BM 128
#define BN 128
#define BK 16
#define ESPLIT 16
#define ERANGE (NE / ESPLIT)
#define ETILES (ERANGE / BN)
#define PM 64
#define PN 64
#define PK 16

// ---------------- Kernel: ||E_e||^2 ----------------
__global__ __launch_bounds__(256) void enorm_kernel(const float* __restrict__ E,
                                                    float* __restrict__ enorm) {
    int wave = threadIdx.x >> 6;
    int lane = threadIdx.x & 63;
    int row = blockIdx.x * 4 + wave;
    const float* er = E + (size_t)row * DIMK;
    float s = 0.f;
#pragma unroll
    for (int k = 0; k < DIMK / 64; ++k) {
        float v = er[lane + k * 64];
        s = fmaf(v, v, s);
    }
#pragma unroll
    for (int off = 32; off > 0; off >>= 1) s += __shfl_down(s, off, 64);
    if (lane == 0) enorm[row] = s;
}

// ---------------- Kernel: pack f32 -> bf16x3 tiled+swizzled ----------------
// A = [Xhi | Xlo | Xhi], B = [Ehi | Ehi | Elo]  (K' = 1536)
// Packed layout: per (tile128, kstep32): 8192-byte image,
//   byte for (r in 0..127, kk in 0..31) = (r*64 + kk*2) ^ ((r&7)<<4)
__global__ __launch_bounds__(256) void pack_kernel(const float* __restrict__ S,
                                                   uint8_t* __restrict__ P,
                                                   int isA) {
    int idx = blockIdx.x * 256 + threadIdx.x;   // rows*192 total
    int row = idx / 192;
    int c = idx - row * 192;
    int kglob = c * 8;
    int blk = kglob >> 9;       // 0,1,2
    int ksrc = kglob & 511;
    const float* src = S + (size_t)row * DIMK + ksrc;
    float4 f0 = *(const float4*)src;
    float4 f1 = *(const float4*)(src + 4);
    float xs[8] = {f0.x, f0.y, f0.z, f0.w, f1.x, f1.y, f1.z, f1.w};
    unsigned short o[8];
#pragma unroll
    for (int j = 0; j < 8; ++j) {
        float x = xs[j];
        __bf16 h = (__bf16)x;
        float rem = x - (float)h;
        __bf16 l = (__bf16)rem;
        __bf16 v;
        if (isA) v = (blk == 1) ? l : h;   // [hi, lo, hi]
        else     v = (blk == 2) ? l : h;   // [hi, hi, lo]
        o[j] = __builtin_bit_cast(unsigned short, v);
    }
    uint4 u;
    u.x = (uint32_t)o[0] | ((uint32_t)o[1] << 16);
    u.y = (uint32_t)o[2] | ((uint32_t)o[3] << 16);
    u.z = (uint32_t)o[4] | ((uint32_t)o[5] << 16);
    u.w = (uint32_t)o[6] | ((uint32_t)o[7] << 16);
    int mb = row >> 7, r = row & 127, kt = kglob >> 5, kk = kglob & 31;
    size_t base = ((size_t)mb * KSTEPS + kt) * TILE_BYTES;
    int byte = (r * 64 + kk * 2) ^ ((r & 7) << 4);
    *(uint4*)(P + base + byte) = u;
}

// ---------------- global -> LDS staging (8 KB, 256 threads) ----------------
__device__ __forceinline__ void stage_8k(void* lds, const void* g, int tid) {
    const int wid = tid >> 6;
    const int lane = tid & 63;
    using gu32 = const __attribute__((address_space(1))) uint32_t;
    using lu32 = __attribute__((address_space(3))) uint32_t;
    const uint8_t* gp = (const uint8_t*)g + (size_t)(wid * 1024 + lane * 16);
    uint8_t* lp = (uint8_t*)lds + wid * 1024;
    __builtin_amdgcn_global_load_lds((gu32*)gp, (lu32*)lp, 16, 0, 0);
    __builtin_amdgcn_global_load_lds((gu32*)(gp + 4096), (lu32*)(lp + 4096), 16, 0, 0);
}

__device__ __forceinline__ void t2merge(float& v1, int& i1, float& v2, int& i2,
                                        float ov, int oi) {
    if (ov < v1 || (ov == v1 && oi < i1)) {
        v2 = v1; i2 = i1; v1 = ov; i1 = oi;
    } else if (ov < v2 || (ov == v2 && oi < i2)) {
        v2 = ov; i2 = oi;
    }
}

// ---------------- Kernel: bf16x3 MFMA dist + top-2 capture ----------------
// grid = 4096 blocks, one 128x128 output tile each, dbuf LDS, 1 barrier/K-step
__global__ __launch_bounds__(256, 4) void dist_mfma_kernel(
    const uint8_t* __restrict__ Ap, const uint8_t* __restrict__ Bp,
    const float* __restrict__ enorm,
    float* __restrict__ candv, int* __restrict__ candi) {
    __shared__ __align__(16) uint8_t As[2][TILE_BYTES];
    __shared__ __align__(16) uint8_t Bs[2][TILE_BYTES];
    __shared__ float t2v[128][2][2];
    __shared__ int t2i[128][2][2];

    const int tid = threadIdx.x;
    const int lane = tid & 63;
    const int wid = tid >> 6;
    const int wr = wid >> 1, wc = wid & 1;
    // bijective XCD swizzle (4096 % 8 == 0): same-mb blocks share an XCD L2
    const int wgid = (blockIdx.x & 7) * 512 + (blockIdx.x >> 3);
    const int mb = wgid >> 6;        // 64 row-blocks of 128
    const int nb = wgid & 63;        // 64 col-blocks of 128
    const int lr = lane & 15;
    const int kq = lane >> 4;

    const uint8_t* gA = Ap + (size_t)mb * KSTEPS * TILE_BYTES;
    const uint8_t* gB = Bp + (size_t)nb * KSTEPS * TILE_BYTES;

    // loop-invariant swizzled LDS byte offsets
    int aoff[4], boff[4];
#pragma unroll
    for (int mi = 0; mi < 4; ++mi) {
        int row = wr * 64 + mi * 16 + lr;
        aoff[mi] = (row * 64 + kq * 16) ^ ((row & 7) << 4);
    }
#pragma unroll
    for (int ni = 0; ni < 4; ++ni) {
        int row = wc * 64 + ni * 16 + lr;
        boff[ni] = (row * 64 + kq * 16) ^ ((row & 7) << 4);
    }

    f32x4 acc[4][4];
#pragma unroll
    for (int mi = 0; mi < 4; ++mi)
#pragma unroll
        for (int ni = 0; ni < 4; ++ni)
            acc[mi][ni] = (f32x4){0.f, 0.f, 0.f, 0.f};

    stage_8k(As[0], gA, tid);
    stage_8k(Bs[0], gB, tid);

    int buf = 0;
    for (int kt = 0; kt < KSTEPS; ++kt) {
        __syncthreads();               // buf fully written (vmcnt drained)
        if (kt + 1 < KSTEPS) {         // prefetch next tile into buf^1
            stage_8k(As[buf ^ 1], gA + (size_t)(kt + 1) * TILE_BYTES, tid);
            stage_8k(Bs[buf ^ 1], gB + (size_t)(kt + 1) * TILE_BYTES, tid);
        }
        bf16x8 af[4], bfr[4];
#pragma unroll
        for (int mi = 0; mi < 4; ++mi) af[mi] = *(const bf16x8*)(As[buf] + aoff[mi]);
#pragma unroll
        for (int ni = 0; ni < 4; ++ni) bfr[ni] = *(const bf16x8*)(Bs[buf] + boff[ni]);
#pragma unroll
        for (int mi = 0; mi < 4; ++mi)
#pragma unroll
            for (int ni = 0; ni < 4; ++ni)
                acc[mi][ni] = __builtin_amdgcn_mfma_f32_16x16x32_bf16(
                    af[mi], bfr[ni], acc[mi][ni], 0, 0, 0);
        buf ^= 1;
    }

    // epilogue: s = enorm - 2*acc ; per-row top-2 over this 128-col tile
    const int e0 = nb * 128 + wc * 64;
#pragma unroll
    for (int mi = 0; mi < 4; ++mi) {
#pragma unroll
        for (int reg = 0; reg < 4; ++reg) {
            int rloc = wr * 64 + mi * 16 + kq * 4 + reg;
            float v1 = 3.4e38f, v2 = 3.4e38f;
            int i1 = 0, i2 = 0;
#pragma unroll
            for (int ni = 0; ni < 4; ++ni) {
                int e = e0 + ni * 16 + lr;
                float s = fmaf(-2.f, acc[mi][ni][reg], enorm[e]);
                t2merge(v1, i1, v2, i2, s, e);
            }
#pragma unroll
            for (int m = 1; m <= 8; m <<= 1) {
                float ov1 = __shfl_xor(v1, m, 64);
                int oi1 = __shfl_xor(i1, m, 64);
                float ov2 = __shfl_xor(v2, m, 64);
                int oi2 = __shfl_xor(i2, m, 64);
                t2merge(v1, i1, v2, i2, ov1, oi1);
                t2merge(v1, i1, v2, i2, ov2, oi2);
            }
            if (lr == 0) {
                t2v[rloc][wc][0] = v1; t2v[rloc][wc][1] = v2;
                t2i[rloc][wc][0] = i1; t2i[rloc][wc][1] = i2;
            }
        }
    }
    __syncthreads();
    if (tid < 128) {
        float rv1 = 3.4e38f, rv2 = 3.4e38f;
        int ri1 = 0, ri2 = 0;
#pragma unroll
        for (int c = 0; c < 2; ++c)
#pragma unroll
            for (int h = 0; h < 2; ++h)
                t2merge(rv1, ri1, rv2, ri2, t2v[tid][c][h], t2i[tid][c][h]);
        int row = mb * 128 + tid;
        size_t o = (size_t)row * (NBLK * 2) + nb * 2;
        candv[o] = rv1; candi[o] = ri1;
        candv[o + 1] = rv2; candi[o + 1] = ri2;
    }
}

// ---------------- Kernel: fp64 refine of candidates -> argmin ----------------
__global__ __launch_bounds__(256) void refine_kernel(
    const float* __restrict__ X, const float* __restrict__ E,
    const float* __restrict__ candv, const int* __restrict__ candi,
    int* __restrict__ ind) {
    const int wid = threadIdx.x >> 6;
    const int lane = threadIdx.x & 63;
    const int row = blockIdx.x * 4 + wid;

    const float* cv = candv + (size_t)row * (NBLK * 2);
    const int* cidx = candi + (size_t)row * (NBLK * 2);
    float v0 = cv[lane], v1 = cv[lane + 64];
    int i0 = cidx[lane], i1 = cidx[lane + 64];

    float vmin = fminf(v0, v1);
#pragma unroll
    for (int off = 32; off > 0; off >>= 1)
        vmin = fminf(vmin, __shfl_xor(vmin, off, 64));

    unsigned long long m0 = __ballot(v0 <= vmin + DELTA);
    unsigned long long m1 = __ballot(v1 <= vmin + DELTA);
    double bestd = 1e300;
    int besti = 0x7fffffff;
    const float* xr = X + (size_t)row * DIMK;
#pragma unroll 1
    for (int half = 0; half < 2; ++half) {
        unsigned long long mask = half ? m1 : m0;
        int myi = half ? i1 : i0;
        while (mask) {
            int src = __ffsll((long long)mask) - 1;
            mask &= mask - 1;
            int e = __shfl(myi, src, 64);
            const float* er = E + (size_t)e * DIMK;
            double s = 0.0;
#pragma unroll
            for (int j = 0; j < 8; ++j) {
                double ev = (double)er[lane * 8 + j];
                double xv = (double)xr[lane * 8 + j];
                s += ev * (ev - 2.0 * xv);
            }
#pragma unroll
            for (int off = 32; off > 0; off >>= 1)
                s += __shfl_xor(s, off, 64);
            if (s < bestd || (s == bestd && e < besti)) { bestd = s; besti = e; }
        }
    }
    if (lane == 0) ind[row] = besti;
}

// ------- f32 fallback: fused dist matmul + per-split argmin -------
__global__ __launch_bounds__(256) void dist_argmin_kernel(
    const float* __restrict__ X, const float* __restrict__ E,
    const float* __restrict__ enorm,
    float* __restrict__ pval, int* __restrict__ pidx) {
    __shared__ float xs[BK][BM + 4];
    __shared__ float es[BK][BN + 4];
    __shared__ float rv[BM][17];
    __shared__ int ri[BM][17];

    const int tid = threadIdx.x;
    const int row0 = blockIdx.y * BM;
    const int e_base = blockIdx.x * ERANGE;
    const int tx = tid & 15;
    const int ty = tid >> 4;

    float minv[8];
    int mini[8];
#pragma unroll
    for (int i = 0; i < 8; ++i) { minv[i] = 3.4e38f; mini[i] = 0; }

    const int lm = tid >> 1;
    const int lk = (tid & 1) * 8;

    for (int et = 0; et < ETILES; ++et) {
        const int e0 = e_base + et * BN;
        float acc[8][8];
#pragma unroll
        for (int i = 0; i < 8; ++i)
#pragma unroll
            for (int j = 0; j < 8; ++j) acc[i][j] = 0.f;

        for (int kt = 0; kt < DIMK / BK; ++kt) {
            const int k0 = kt * BK;
            {
                const float* src = X + (size_t)(row0 + lm) * DIMK + k0 + lk;
                float4 v0 = *(const float4*)(src);
                float4 v1 = *(const float4*)(src + 4);
                xs[lk + 0][lm] = v0.x; xs[lk + 1][lm] = v0.y;
                xs[lk + 2][lm] = v0.z; xs[lk + 3][lm] = v0.w;
                xs[lk + 4][lm] = v1.x; xs[lk + 5][lm] = v1.y;
                xs[lk + 6][lm] = v1.z; xs[lk + 7][lm] = v1.w;
            }
            {
                const float* src = E + (size_t)(e0 + lm) * DIMK + k0 + lk;
                float4 v0 = *(const float4*)(src);
                float4 v1 = *(const float4*)(src + 4);
                es[lk + 0][lm] = v0.x; es[lk + 1][lm] = v0.y;
                es[lk + 2][lm] = v0.z; es[lk + 3][lm] = v0.w;
                es[lk + 4][lm] = v1.x; es[lk + 5][lm] = v1.y;
                es[lk + 6][lm] = v1.z; es[lk + 7][lm] = v1.w;
            }
            __syncthreads();
#pragma unroll
            for (int k = 0; k < BK; ++k) {
                float4 a0 = *(const float4*)&xs[k][ty * 8];
                float4 a1 = *(const float4*)&xs[k][ty * 8 + 4];
                float4 b0 = *(const float4*)&es[k][tx * 8];
                float4 b1 = *(const float4*)&es[k][tx * 8 + 4];
                float av[8] = {a0.x, a0.y, a0.z, a0.w, a1.x, a1.y, a1.z, a1.w};
                float bv[8] = {b0.x, b0.y, b0.z, b0.w, b1.x, b1.y, b1.z, b1.w};
#pragma unroll
                for (int i = 0; i < 8; ++i)
#pragma unroll
                    for (int j = 0; j < 8; ++j)
                        acc[i][j] = fmaf(av[i], bv[j], acc[i][j]);
            }
            __syncthreads();
        }
#pragma unroll
        for (int j = 0; j < 8; ++j) {
            const int e = e0 + tx * 8 + j;
            const float en = enorm[e];
#pragma unroll
            for (int i = 0; i < 8; ++i) {
                const float s = fmaf(-2.f, acc[i][j], en);
                if (s < minv[i]) { minv[i] = s; mini[i] = e; }
            }
        }
    }
#pragma unroll
    for (int i = 0; i < 8; ++i) {
        rv[ty * 8 + i][tx] = minv[i];
        ri[ty * 8 + i][tx] = mini[i];
    }
    __syncthreads();
    if (tid < BM) {
        float bv = rv[tid][0];
        int bi = ri[tid][0];
#pragma unroll
        for (int t = 1; t < 16; ++t) {
            float vv = rv[tid][t];
            int ix = ri[tid][t];
            if (vv < bv || (vv == bv && ix < bi)) { bv = vv; bi = ix; }
        }
        const int row = row0 + tid;
        pval[(size_t)row * ESPLIT + blockIdx.x] = bv;
        pidx[(size_t)row * ESPLIT + blockIdx.x] = bi;
    }
}

__global__ __launch_bounds__(256) void reduce_argmin_kernel(
    const float* __restrict__ pval, const int* __restrict__ pidx,
    int* __restrict__ ind) {
    int r = blockIdx.x * blockDim.x + threadIdx.x;
    if (r >= NR) return;
    float bv = pval[(size_t)r * ESPLIT];
    int bi = pidx[(size_t)r * ESPLIT];
#pragma unroll
    for (int s = 1; s < ESPLIT; ++s) {
        float v = pval[(size_t)r * ESPLIT + s];
        int ix = pidx[(size_t)r * ESPLIT + s];
        if (v < bv || (v == bv && ix < bi)) { bv = v; bi = ix; }
    }
    ind[r] = bi;
}

// ------- proj: out = x + (x - E[ind]) @ W^T + b -------
__global__ __launch_bounds__(256) void proj_kernel(
    const float* __restrict__ X, const float* __restrict__ E,
    const int* __restrict__ ind,
    const float* __restrict__ W, const float* __restrict__ Bv,
    float* __restrict__ Out) {
    __shared__ float as_[PK][PM + 4];
    __shared__ float bs[PK][PN + 4];
    __shared__ int inds[PM];

    const int tid = threadIdx.x;
    const int row0 = blockIdx.y * PM;
    const int col0 = blockIdx.x * PN;

    if (tid < PM) inds[tid] = ind[row0 + tid];
    __syncthreads();

    const int tx = tid & 15;
    const int ty = tid >> 4;

    float acc[4][4];
#pragma unroll
    for (int i = 0; i < 4; ++i)
#pragma unroll
        for (int j = 0; j < 4; ++j) acc[i][j] = 0.f;

    const int lm = tid >> 2;
    const int lk = (tid & 3) * 4;

    for (int kt = 0; kt < DIMK / PK; ++kt) {
        const int k0 = kt * PK;
        {
            float4 xv = *(const float4*)(X + (size_t)(row0 + lm) * DIMK + k0 + lk);
            float4 qv = *(const float4*)(E + (size_t)inds[lm] * DIMK + k0 + lk);
            as_[lk + 0][lm] = xv.x - qv.x;
            as_[lk + 1][lm] = xv.y - qv.y;
            as_[lk + 2][lm] = xv.z - qv.z;
            as_[lk + 3][lm] = xv.w - qv.w;
        }
        {
            float4 wv = *(const float4*)(W + (size_t)(col0 + lm) * DIMK + k0 + lk);
            bs[lk + 0][lm] = wv.x; bs[lk + 1][lm] = wv.y;
            bs[lk + 2][lm] = wv.z; bs[lk + 3][lm] = wv.w;
        }
        __syncthreads();
#pragma unroll
        for (int k = 0; k < PK; ++k) {
            float4 a = *(const float4*)&as_[k][ty * 4];
            float4 b = *(const float4*)&bs[k][tx * 4];
            float av[4] = {a.x, a.y, a.z, a.w};
            float bvv[4] = {b.x, b.y, b.z, b.w};
#pragma unroll
            for (int i = 0; i < 4; ++i)
#pragma unroll
                for (int j = 0; j < 4; ++j)
                    acc[i][j] = fmaf(av[i], bvv[j], acc[i][j]);
        }
        __syncthreads();
    }

#pragma unroll
    for (int j = 0; j < 4; ++j) {
        const int col = col0 + tx * 4 + j;
        const float bias = Bv[col];
#pragma unroll
        for (int i = 0; i < 4; ++i) {
            const int row = row0 + ty * 4 + i;
            Out[(size_t)row * DIMK + col] =
                X[(size_t)row * DIMK + col] + acc[i][j] + bias;
        }
    }
}

extern "C" void kernel_launch(void* const* d_in, const int* in_sizes, int n_in,
                              void* d_out, int out_size, void* d_ws, size_t ws_size,
                              hipStream_t stream) {
    const float* X = (const float*)d_in[0];
    const float* E = (const float*)d_in[1];
    const float* W = (const float*)d_in[2];
    const float* B = (const float*)d_in[3];
    float* out = (float*)d_out;

    const size_t packBytes = (size_t)NR * KP * 2;     // 24 MB each
    const size_t candN = (size_t)NR * NBLK * 2;       // 1M entries
    const size_t needMFMA = packBytes * 2 + NE * 4 + candN * 8 + NR * 4;

    if (ws_size >= needMFMA) {
        uint8_t* Ap = (uint8_t*)d_ws;
        uint8_t* Bp = Ap + packBytes;
        float* enorm = (float*)(Bp + packBytes);
        float* candv = enorm + NE;
        int* candi = (int*)(candv + candN);
        int* ind = candi + candN;

        hipLaunchKernelGGL(enorm_kernel, dim3(NE / 4), dim3(256), 0, stream, E, enorm);
        hipLaunchKernelGGL(pack_kernel, dim3(NR * 192 / 256), dim3(256), 0, stream,
                           X, Ap, 1);
        hipLaunchKernelGGL(pack_kernel, dim3(NE * 192 / 256), dim3(256), 0, stream,
                           E, Bp, 0);
        hipLaunchKernelGGL(dist_mfma_kernel, dim3(4096), dim3(256), 0,
                           stream, Ap, Bp, enorm, candv, candi);
        hipLaunchKernelGGL(refine_kernel, dim3(NR / 4), dim3(256), 0, stream,
                           X, E, candv, candi, ind);
        hipLaunchKernelGGL(proj_kernel, dim3(DIMK / PN, NR / PM), dim3(256), 0, stream,
                           X, E, ind, W, B, out);
    } else {
        float* enorm = (float*)d_ws;
        float* pval = enorm + NE;
        int* pidx = (int*)(pval + (size_t)NR * ESPLIT);
        int* ind = pidx + (size_t)NR * ESPLIT;

        hipLaunchKernelGGL(enorm_kernel, dim3(NE / 4), dim3(256), 0, stream, E, enorm);
        hipLaunchKernelGGL(dist_argmin_kernel, dim3(ESPLIT, NR / BM), dim3(256), 0,
                           stream, X, E, enorm, pval, pidx);
        hipLaunchKernelGGL(reduce_argmin_kernel, dim3(NR / 256), dim3(256), 0, stream,
                           pval, pidx, ind);
        hipLaunchKernelGGL(proj_kernel, dim3(DIMK / PN, NR / PM), dim3(256), 0, stream,
                           X, E, ind, W, B, out);
    }
}

// Round 4
// 694.812 us; speedup vs baseline: 1.4871x; 1.2088x over previous
//
#include <hip/hip_runtime.h>
#include <cstdint>

#define NR 8192
#define DIMK 512
#define NE 8192

// ---------------- MFMA path parameters ----------------
#define KP 512             // plain bf16 (top-2 + fp64 refine absorbs the error)
#define GBK 32             // K-step
#define KSTEPS (KP / GBK)  // 16
#define TILE_BYTES 8192    // 128 rows x 32 k x 2B per K-step image
#define NBLK 64            // 64 col-blocks of 128 codes
#define DELTA 1.0f         // refine window: ~12 sigma of bf16 dist error

typedef __bf16 bf16x8 __attribute__((ext_vector_type(8)));
typedef float f32x4 __attribute__((ext_vector_type(4)));

// f32 fallback tiling
#define BM 128
#define BN 128
#define BK 16
#define ESPLIT 16
#define ERANGE (NE / ESPLIT)
#define ETILES (ERANGE / BN)
#define PM 64
#define PN 64
#define PK 16

// ---------------- Kernel: ||E_e||^2 ----------------
__global__ __launch_bounds__(256) void enorm_kernel(const float* __restrict__ E,
                                                    float* __restrict__ enorm) {
    int wave = threadIdx.x >> 6;
    int lane = threadIdx.x & 63;
    int row = blockIdx.x * 4 + wave;
    const float* er = E + (size_t)row * DIMK;
    float s = 0.f;
#pragma unroll
    for (int k = 0; k < DIMK / 64; ++k) {
        float v = er[lane + k * 64];
        s = fmaf(v, v, s);
    }
#pragma unroll
    for (int off = 32; off > 0; off >>= 1) s += __shfl_down(s, off, 64);
    if (lane == 0) enorm[row] = s;
}

// ---------------- Kernel: pack f32 -> bf16 tiled+swizzled ----------------
// Packed layout: per (tile128, kstep32): 8192-byte image,
//   byte for (r in 0..127, kk in 0..31) = (r*64 + kk*2) ^ ((r&7)<<4)
__global__ __launch_bounds__(256) void pack_kernel(const float* __restrict__ S,
                                                   uint8_t* __restrict__ P) {
    int idx = blockIdx.x * 256 + threadIdx.x;   // rows*64 total
    int row = idx >> 6;
    int c = idx & 63;
    int kglob = c * 8;
    const float* src = S + (size_t)row * DIMK + kglob;
    float4 f0 = *(const float4*)src;
    float4 f1 = *(const float4*)(src + 4);
    float xs[8] = {f0.x, f0.y, f0.z, f0.w, f1.x, f1.y, f1.z, f1.w};
    unsigned short o[8];
#pragma unroll
    for (int j = 0; j < 8; ++j) {
        __bf16 h = (__bf16)xs[j];
        o[j] = __builtin_bit_cast(unsigned short, h);
    }
    uint4 u;
    u.x = (uint32_t)o[0] | ((uint32_t)o[1] << 16);
    u.y = (uint32_t)o[2] | ((uint32_t)o[3] << 16);
    u.z = (uint32_t)o[4] | ((uint32_t)o[5] << 16);
    u.w = (uint32_t)o[6] | ((uint32_t)o[7] << 16);
    int mb = row >> 7, r = row & 127, kt = kglob >> 5, kk = kglob & 31;
    size_t base = ((size_t)mb * KSTEPS + kt) * TILE_BYTES;
    int byte = (r * 64 + kk * 2) ^ ((r & 7) << 4);
    *(uint4*)(P + base + byte) = u;
}

// ---------------- global -> LDS staging (8 KB, 256 threads) ----------------
__device__ __forceinline__ void stage_8k(void* lds, const void* g, int tid) {
    const int wid = tid >> 6;
    const int lane = tid & 63;
    using gu32 = const __attribute__((address_space(1))) uint32_t;
    using lu32 = __attribute__((address_space(3))) uint32_t;
    const uint8_t* gp = (const uint8_t*)g + (size_t)(wid * 1024 + lane * 16);
    uint8_t* lp = (uint8_t*)lds + wid * 1024;
    __builtin_amdgcn_global_load_lds((gu32*)gp, (lu32*)lp, 16, 0, 0);
    __builtin_amdgcn_global_load_lds((gu32*)(gp + 4096), (lu32*)(lp + 4096), 16, 0, 0);
}

__device__ __forceinline__ void t2merge(float& v1, int& i1, float& v2, int& i2,
                                        float ov, int oi) {
    if (ov < v1 || (ov == v1 && oi < i1)) {
        v2 = v1; i2 = i1; v1 = ov; i1 = oi;
    } else if (ov < v2 || (ov == v2 && oi < i2)) {
        v2 = ov; i2 = oi;
    }
}

// ---------------- Kernel: bf16 MFMA dist + top-2 capture ----------------
// grid = 4096. XCD-sliced over nb: each XCD owns an 8-nb (1 MB) B slice that
// stays L2-resident; 8 consecutive blocks share one A-tile (mb).
__global__ __launch_bounds__(256, 4) void dist_mfma_kernel(
    const uint8_t* __restrict__ Ap, const uint8_t* __restrict__ Bp,
    const float* __restrict__ enorm,
    float* __restrict__ candv, int* __restrict__ candi) {
    __shared__ __align__(16) uint8_t As[2][TILE_BYTES];
    __shared__ __align__(16) uint8_t Bs[2][TILE_BYTES];
    __shared__ float t2v[128][2][2];
    __shared__ int t2i[128][2][2];

    const int tid = threadIdx.x;
    const int lane = tid & 63;
    const int wid = tid >> 6;
    const int wr = wid >> 1, wc = wid & 1;
    // XCD slicing: xcd = bid&7 owns nb in [xcd*8, xcd*8+8); within an XCD,
    // 8 consecutive slots share the same mb (A-tile L2 reuse).
    const int xcd = blockIdx.x & 7;
    const int slot = blockIdx.x >> 3;      // 0..511
    const int mb = slot >> 3;              // 0..63
    const int nb = xcd * 8 + (slot & 7);   // 0..63
    const int lr = lane & 15;
    const int kq = lane >> 4;

    const uint8_t* gA = Ap + (size_t)mb * KSTEPS * TILE_BYTES;
    const uint8_t* gB = Bp + (size_t)nb * KSTEPS * TILE_BYTES;

    // loop-invariant swizzled LDS byte offsets
    int aoff[4], boff[4];
#pragma unroll
    for (int mi = 0; mi < 4; ++mi) {
        int row = wr * 64 + mi * 16 + lr;
        aoff[mi] = (row * 64 + kq * 16) ^ ((row & 7) << 4);
    }
#pragma unroll
    for (int ni = 0; ni < 4; ++ni) {
        int row = wc * 64 + ni * 16 + lr;
        boff[ni] = (row * 64 + kq * 16) ^ ((row & 7) << 4);
    }

    f32x4 acc[4][4];
#pragma unroll
    for (int mi = 0; mi < 4; ++mi)
#pragma unroll
        for (int ni = 0; ni < 4; ++ni)
            acc[mi][ni] = (f32x4){0.f, 0.f, 0.f, 0.f};

    stage_8k(As[0], gA, tid);
    stage_8k(Bs[0], gB, tid);

    int buf = 0;
    for (int kt = 0; kt < KSTEPS; ++kt) {
        __syncthreads();               // buf fully written (vmcnt drained)
        if (kt + 1 < KSTEPS) {         // prefetch next tile into buf^1
            stage_8k(As[buf ^ 1], gA + (size_t)(kt + 1) * TILE_BYTES, tid);
            stage_8k(Bs[buf ^ 1], gB + (size_t)(kt + 1) * TILE_BYTES, tid);
        }
        bf16x8 af[4], bfr[4];
#pragma unroll
        for (int mi = 0; mi < 4; ++mi) af[mi] = *(const bf16x8*)(As[buf] + aoff[mi]);
#pragma unroll
        for (int ni = 0; ni < 4; ++ni) bfr[ni] = *(const bf16x8*)(Bs[buf] + boff[ni]);
#pragma unroll
        for (int mi = 0; mi < 4; ++mi)
#pragma unroll
            for (int ni = 0; ni < 4; ++ni)
                acc[mi][ni] = __builtin_amdgcn_mfma_f32_16x16x32_bf16(
                    af[mi], bfr[ni], acc[mi][ni], 0, 0, 0);
        buf ^= 1;
    }

    // epilogue: s = enorm - 2*acc ; per-row top-2 over this 128-col tile
    const int e0 = nb * 128 + wc * 64;
#pragma unroll
    for (int mi = 0; mi < 4; ++mi) {
#pragma unroll
        for (int reg = 0; reg < 4; ++reg) {
            int rloc = wr * 64 + mi * 16 + kq * 4 + reg;
            float v1 = 3.4e38f, v2 = 3.4e38f;
            int i1 = 0, i2 = 0;
#pragma unroll
            for (int ni = 0; ni < 4; ++ni) {
                int e = e0 + ni * 16 + lr;
                float s = fmaf(-2.f, acc[mi][ni][reg], enorm[e]);
                t2merge(v1, i1, v2, i2, s, e);
            }
#pragma unroll
            for (int m = 1; m <= 8; m <<= 1) {
                float ov1 = __shfl_xor(v1, m, 64);
                int oi1 = __shfl_xor(i1, m, 64);
                float ov2 = __shfl_xor(v2, m, 64);
                int oi2 = __shfl_xor(i2, m, 64);
                t2merge(v1, i1, v2, i2, ov1, oi1);
                t2merge(v1, i1, v2, i2, ov2, oi2);
            }
            if (lr == 0) {
                t2v[rloc][wc][0] = v1; t2v[rloc][wc][1] = v2;
                t2i[rloc][wc][0] = i1; t2i[rloc][wc][1] = i2;
            }
        }
    }
    __syncthreads();
    if (tid < 128) {
        float rv1 = 3.4e38f, rv2 = 3.4e38f;
        int ri1 = 0, ri2 = 0;
#pragma unroll
        for (int c = 0; c < 2; ++c)
#pragma unroll
            for (int h = 0; h < 2; ++h)
                t2merge(rv1, ri1, rv2, ri2, t2v[tid][c][h], t2i[tid][c][h]);
        int row = mb * 128 + tid;
        size_t o = (size_t)row * (NBLK * 2) + nb * 2;
        candv[o] = rv1; candi[o] = ri1;
        candv[o + 1] = rv2; candi[o + 1] = ri2;
    }
}

// ---------------- Kernel: fp64 refine of candidates -> argmin ----------------
__global__ __launch_bounds__(256) void refine_kernel(
    const float* __restrict__ X, const float* __restrict__ E,
    const float* __restrict__ candv, const int* __restrict__ candi,
    int* __restrict__ ind) {
    const int wid = threadIdx.x >> 6;
    const int lane = threadIdx.x & 63;
    const int row = blockIdx.x * 4 + wid;

    const float* cv = candv + (size_t)row * (NBLK * 2);
    const int* cidx = candi + (size_t)row * (NBLK * 2);
    float v0 = cv[lane], v1 = cv[lane + 64];
    int i0 = cidx[lane], i1 = cidx[lane + 64];

    float vmin = fminf(v0, v1);
#pragma unroll
    for (int off = 32; off > 0; off >>= 1)
        vmin = fminf(vmin, __shfl_xor(vmin, off, 64));

    unsigned long long m0 = __ballot(v0 <= vmin + DELTA);
    unsigned long long m1 = __ballot(v1 <= vmin + DELTA);
    double bestd = 1e300;
    int besti = 0x7fffffff;
    const float* xr = X + (size_t)row * DIMK;
#pragma unroll 1
    for (int half = 0; half < 2; ++half) {
        unsigned long long mask = half ? m1 : m0;
        int myi = half ? i1 : i0;
        while (mask) {
            int src = __ffsll((long long)mask) - 1;
            mask &= mask - 1;
            int e = __shfl(myi, src, 64);
            const float* er = E + (size_t)e * DIMK;
            double s = 0.0;
#pragma unroll
            for (int j = 0; j < 8; ++j) {
                double ev = (double)er[lane * 8 + j];
                double xv = (double)xr[lane * 8 + j];
                s += ev * (ev - 2.0 * xv);
            }
#pragma unroll
            for (int off = 32; off > 0; off >>= 1)
                s += __shfl_xor(s, off, 64);
            if (s < bestd || (s == bestd && e < besti)) { bestd = s; besti = e; }
        }
    }
    if (lane == 0) ind[row] = besti;
}

// ------- f32 fallback: fused dist matmul + per-split argmin -------
__global__ __launch_bounds__(256) void dist_argmin_kernel(
    const float* __restrict__ X, const float* __restrict__ E,
    const float* __restrict__ enorm,
    float* __restrict__ pval, int* __restrict__ pidx) {
    __shared__ float xs[BK][BM + 4];
    __shared__ float es[BK][BN + 4];
    __shared__ float rv[BM][17];
    __shared__ int ri[BM][17];

    const int tid = threadIdx.x;
    const int row0 = blockIdx.y * BM;
    const int e_base = blockIdx.x * ERANGE;
    const int tx = tid & 15;
    const int ty = tid >> 4;

    float minv[8];
    int mini[8];
#pragma unroll
    for (int i = 0; i < 8; ++i) { minv[i] = 3.4e38f; mini[i] = 0; }

    const int lm = tid >> 1;
    const int lk = (tid & 1) * 8;

    for (int et = 0; et < ETILES; ++et) {
        const int e0 = e_base + et * BN;
        float acc[8][8];
#pragma unroll
        for (int i = 0; i < 8; ++i)
#pragma unroll
            for (int j = 0; j < 8; ++j) acc[i][j] = 0.f;

        for (int kt = 0; kt < DIMK / BK; ++kt) {
            const int k0 = kt * BK;
            {
                const float* src = X + (size_t)(row0 + lm) * DIMK + k0 + lk;
                float4 v0 = *(const float4*)(src);
                float4 v1 = *(const float4*)(src + 4);
                xs[lk + 0][lm] = v0.x; xs[lk + 1][lm] = v0.y;
                xs[lk + 2][lm] = v0.z; xs[lk + 3][lm] = v0.w;
                xs[lk + 4][lm] = v1.x; xs[lk + 5][lm] = v1.y;
                xs[lk + 6][lm] = v1.z; xs[lk + 7][lm] = v1.w;
            }
            {
                const float* src = E + (size_t)(e0 + lm) * DIMK + k0 + lk;
                float4 v0 = *(const float4*)(src);
                float4 v1 = *(const float4*)(src + 4);
                es[lk + 0][lm] = v0.x; es[lk + 1][lm] = v0.y;
                es[lk + 2][lm] = v0.z; es[lk + 3][lm] = v0.w;
                es[lk + 4][lm] = v1.x; es[lk + 5][lm] = v1.y;
                es[lk + 6][lm] = v1.z; es[lk + 7][lm] = v1.w;
            }
            __syncthreads();
#pragma unroll
            for (int k = 0; k < BK; ++k) {
                float4 a0 = *(const float4*)&xs[k][ty * 8];
                float4 a1 = *(const float4*)&xs[k][ty * 8 + 4];
                float4 b0 = *(const float4*)&es[k][tx * 8];
                float4 b1 = *(const float4*)&es[k][tx * 8 + 4];
                float av[8] = {a0.x, a0.y, a0.z, a0.w, a1.x, a1.y, a1.z, a1.w};
                float bv[8] = {b0.x, b0.y, b0.z, b0.w, b1.x, b1.y, b1.z, b1.w};
#pragma unroll
                for (int i = 0; i < 8; ++i)
#pragma unroll
                    for (int j = 0; j < 8; ++j)
                        acc[i][j] = fmaf(av[i], bv[j], acc[i][j]);
            }
            __syncthreads();
        }
#pragma unroll
        for (int j = 0; j < 8; ++j) {
            const int e = e0 + tx * 8 + j;
            const float en = enorm[e];
#pragma unroll
            for (int i = 0; i < 8; ++i) {
                const float s = fmaf(-2.f, acc[i][j], en);
                if (s < minv[i]) { minv[i] = s; mini[i] = e; }
            }
        }
    }
#pragma unroll
    for (int i = 0; i < 8; ++i) {
        rv[ty * 8 + i][tx] = minv[i];
        ri[ty * 8 + i][tx] = mini[i];
    }
    __syncthreads();
    if (tid < BM) {
        float bv = rv[tid][0];
        int bi = ri[tid][0];
#pragma unroll
        for (int t = 1; t < 16; ++t) {
            float vv = rv[tid][t];
            int ix = ri[tid][t];
            if (vv < bv || (vv == bv && ix < bi)) { bv = vv; bi = ix; }
        }
        const int row = row0 + tid;
        pval[(size_t)row * ESPLIT + blockIdx.x] = bv;
        pidx[(size_t)row * ESPLIT + blockIdx.x] = bi;
    }
}

__global__ __launch_bounds__(256) void reduce_argmin_kernel(
    const float* __restrict__ pval, const int* __restrict__ pidx,
    int* __restrict__ ind) {
    int r = blockIdx.x * blockDim.x + threadIdx.x;
    if (r >= NR) return;
    float bv = pval[(size_t)r * ESPLIT];
    int bi = pidx[(size_t)r * ESPLIT];
#pragma unroll
    for (int s = 1; s < ESPLIT; ++s) {
        float v = pval[(size_t)r * ESPLIT + s];
        int ix = pidx[(size_t)r * ESPLIT + s];
        if (v < bv || (v == bv && ix < bi)) { bv = v; bi = ix; }
    }
    ind[r] = bi;
}

// ------- proj: out = x + (x - E[ind]) @ W^T + b -------
__global__ __launch_bounds__(256) void proj_kernel(
    const float* __restrict__ X, const float* __restrict__ E,
    const int* __restrict__ ind,
    const float* __restrict__ W, const float* __restrict__ Bv,
    float* __restrict__ Out) {
    __shared__ float as_[PK][PM + 4];
    __shared__ float bs[PK][PN + 4];
    __shared__ int inds[PM];

    const int tid = threadIdx.x;
    const int row0 = blockIdx.y * PM;
    const int col0 = blockIdx.x * PN;

    if (tid < PM) inds[tid] = ind[row0 + tid];
    __syncthreads();

    const int tx = tid & 15;
    const int ty = tid >> 4;

    float acc[4][4];
#pragma unroll
    for (int i = 0; i < 4; ++i)
#pragma unroll
        for (int j = 0; j < 4; ++j) acc[i][j] = 0.f;

    const int lm = tid >> 2;
    const int lk = (tid & 3) * 4;

    for (int kt = 0; kt < DIMK / PK; ++kt) {
        const int k0 = kt * PK;
        {
            float4 xv = *(const float4*)(X + (size_t)(row0 + lm) * DIMK + k0 + lk);
            float4 qv = *(const float4*)(E + (size_t)inds[lm] * DIMK + k0 + lk);
            as_[lk + 0][lm] = xv.x - qv.x;
            as_[lk + 1][lm] = xv.y - qv.y;
            as_[lk + 2][lm] = xv.z - qv.z;
            as_[lk + 3][lm] = xv.w - qv.w;
        }
        {
            float4 wv = *(const float4*)(W + (size_t)(col0 + lm) * DIMK + k0 + lk);
            bs[lk + 0][lm] = wv.x; bs[lk + 1][lm] = wv.y;
            bs[lk + 2][lm] = wv.z; bs[lk + 3][lm] = wv.w;
        }
        __syncthreads();
#pragma unroll
        for (int k = 0; k < PK; ++k) {
            float4 a = *(const float4*)&as_[k][ty * 4];
            float4 b = *(const float4*)&bs[k][tx * 4];
            float av[4] = {a.x, a.y, a.z, a.w};
            float bvv[4] = {b.x, b.y, b.z, b.w};
#pragma unroll
            for (int i = 0; i < 4; ++i)
#pragma unroll
                for (int j = 0; j < 4; ++j)
                    acc[i][j] = fmaf(av[i], bvv[j], acc[i][j]);
        }
        __syncthreads();
    }

#pragma unroll
    for (int j = 0; j < 4; ++j) {
        const int col = col0 + tx * 4 + j;
        const float bias = Bv[col];
#pragma unroll
        for (int i = 0; i < 4; ++i) {
            const int row = row0 + ty * 4 + i;
            Out[(size_t)row * DIMK + col] =
                X[(size_t)row * DIMK + col] + acc[i][j] + bias;
        }
    }
}

extern "C" void kernel_launch(void* const* d_in, const int* in_sizes, int n_in,
                              void* d_out, int out_size, void* d_ws, size_t ws_size,
                              hipStream_t stream) {
    const float* X = (const float*)d_in[0];
    const float* E = (const float*)d_in[1];
    const float* W = (const float*)d_in[2];
    const float* B = (const float*)d_in[3];
    float* out = (float*)d_out;

    const size_t packBytes = (size_t)NR * KP * 2;     // 8 MB each
    const size_t candN = (size_t)NR * NBLK * 2;       // 1M entries
    const size_t needMFMA = packBytes * 2 + NE * 4 + candN * 8 + NR * 4;

    if (ws_size >= needMFMA) {
        uint8_t* Ap = (uint8_t*)d_ws;
        uint8_t* Bp = Ap + packBytes;
        float* enorm = (float*)(Bp + packBytes);
        float* candv = enorm + NE;
        int* candi = (int*)(candv + candN);
        int* ind = candi + candN;

        hipLaunchKernelGGL(enorm_kernel, dim3(NE / 4), dim3(256), 0, stream, E, enorm);
        hipLaunchKernelGGL(pack_kernel, dim3(NR / 4), dim3(256), 0, stream, X, Ap);
        hipLaunchKernelGGL(pack_kernel, dim3(NE / 4), dim3(256), 0, stream, E, Bp);
        hipLaunchKernelGGL(dist_mfma_kernel, dim3(4096), dim3(256), 0,
                           stream, Ap, Bp, enorm, candv, candi);
        hipLaunchKernelGGL(refine_kernel, dim3(NR / 4), dim3(256), 0, stream,
                           X, E, candv, candi, ind);
        hipLaunchKernelGGL(proj_kernel, dim3(DIMK / PN, NR / PM), dim3(256), 0, stream,
                           X, E, ind, W, B, out);
    } else {
        float* enorm = (float*)d_ws;
        float* pval = enorm + NE;
        int* pidx = (int*)(pval + (size_t)NR * ESPLIT);
        int* ind = pidx + (size_t)NR * ESPLIT;

        hipLaunchKernelGGL(enorm_kernel, dim3(NE / 4), dim3(256), 0, stream, E, enorm);
        hipLaunchKernelGGL(dist_argmin_kernel, dim3(ESPLIT, NR / BM), dim3(256), 0,
                           stream, X, E, enorm, pval, pidx);
        hipLaunchKernelGGL(reduce_argmin_kernel, dim3(NR / 256), dim3(256), 0, stream,
                           pval, pidx, ind);
        hipLaunchKernelGGL(proj_kernel, dim3(DIMK / PN, NR / PM), dim3(256), 0, stream,
                           X, E, ind, W, B, out);
    }
}